// Round 1
// baseline (479.493 us; speedup 1.0000x reference)
//
#include <hip/hip_runtime.h>
#include <hip/hip_bf16.h>

// Problem: B=256, T=64, S=16, U=4.
// x: (B, T, S, S) fp32 ; W: (P=256, O=1024, K=64) fp32 ; bias: (256, 1024) fp32
// out: (B, T, 64, 64) fp32
// y[p,b,o] = sum_k x[b,k,p] * W[p,o,k] + bias[p,o]
// out[b][t][si*4+ui][sj*4+uj], o = t*16 + ui*4 + uj, p = si*16 + sj

#define P_PIX 256
#define BATCH 256
#define KDIM 64
#define ODIM 1024
#define LDA 72   // LDS row stride in bf16 units (144 B = 9 x 16B, keeps b128 alignment, breaks pow2 banks)

using bf16x8 = __attribute__((ext_vector_type(8))) short;
using f32x4  = __attribute__((ext_vector_type(4))) float;

// ---------------- Kernel 1: transpose + convert x -> xp (P, B*T) bf16 ----------------
// x viewed as (R=16384, P=256) row-major; xp[p][r] = bf16(x[r][p]).
__global__ __launch_bounds__(256) void transpose_convert(
    const float* __restrict__ x, __hip_bfloat16* __restrict__ xp)
{
    __shared__ float tile[64][65];
    const int R = BATCH * KDIM;  // 16384
    int p0 = (blockIdx.x & 3) * 64;
    int r0 = (blockIdx.x >> 2) * 64;
    int tp = threadIdx.x & 63;
    int t4 = threadIdx.x >> 6;  // 0..3
    #pragma unroll
    for (int i = 0; i < 16; ++i) {
        int r = t4 + i * 4;
        tile[r][tp] = x[(size_t)(r0 + r) * P_PIX + p0 + tp];
    }
    __syncthreads();
    #pragma unroll
    for (int i = 0; i < 16; ++i) {
        int pl = t4 + i * 4;
        xp[(size_t)(p0 + pl) * R + r0 + tp] = __float2bfloat16(tile[tp][pl]);
    }
}

// ---------------- Kernel 2: per-pixel GEMM 128x128 tile + shuffle epilogue ----------------
// Grid swizzle: g = q*32 + sjmod4*8 + nt ; q = ((si*4 + sjg)*2 + mt)
// -> the 4 blocks sharing an output 64B line (sjmod4 = 0..3) share g%8 (same-XCD heuristic)
//    and are <=24 apart in dispatch order, so L2 merges their 16B partial-line writes.
__global__ __launch_bounds__(256, 2) void gemm_pixel(
    const __hip_bfloat16* __restrict__ xp,  // (256, 256, 64) bf16
    const float* __restrict__ W,            // (256, 1024, 64) fp32
    const float* __restrict__ bias,         // (256, 1024) fp32
    float* __restrict__ out)                // (256, 64, 64, 64) fp32
{
    __shared__ __hip_bfloat16 As[128 * LDA];  // [m][k]
    __shared__ __hip_bfloat16 Bs[128 * LDA];  // [n][k]

    int g = blockIdx.x;
    int nt     = g & 7;
    int sjmod4 = (g >> 3) & 3;
    int q      = g >> 5;          // 0..127
    int mt  = q & 1;
    int sjg = (q >> 1) & 3;
    int si  = q >> 3;             // 0..15
    int p  = si * 16 + sjg * 4 + sjmod4;
    int m0 = mt * 128;
    int n0 = nt * 128;
    int tid = threadIdx.x;

    // ---- stage A: 128x64 bf16, contiguous 16 KB ----
    {
        const uint4* src = (const uint4*)(xp + (size_t)p * (BATCH * KDIM) + (size_t)m0 * KDIM);
        #pragma unroll
        for (int c = 0; c < 4; ++c) {
            int idx = c * 256 + tid;          // 1024 x 16B
            int row = idx >> 3, ch = idx & 7; // row 0..127, 8 chunks/row
            uint4 v = src[idx];
            *(uint4*)(&As[row * LDA + ch * 8]) = v;
        }
    }
    // ---- stage B: 128x64 fp32 -> bf16 ----
    {
        const float4* src = (const float4*)(W + (size_t)p * (ODIM * KDIM) + (size_t)n0 * KDIM);
        #pragma unroll
        for (int c = 0; c < 8; ++c) {
            int idx = c * 256 + tid;            // 2048 x 16B
            int row = idx >> 4, ch = idx & 15;  // row 0..127, 16 chunks/row
            float4 v = src[idx];
            __hip_bfloat16 h[4];
            h[0] = __float2bfloat16(v.x); h[1] = __float2bfloat16(v.y);
            h[2] = __float2bfloat16(v.z); h[3] = __float2bfloat16(v.w);
            *(uint2*)(&Bs[row * LDA + ch * 4]) = *(const uint2*)h;
        }
    }
    __syncthreads();

    int wave = tid >> 6;
    int lane = tid & 63;
    int wm = (wave & 1) * 64;
    int wn = (wave >> 1) * 64;
    int lrow = lane & 15;
    int quad = lane >> 4;

    f32x4 acc[4][4] = {};
    #pragma unroll
    for (int ks = 0; ks < 2; ++ks) {
        bf16x8 a[4], b[4];
        int kof = ks * 32 + quad * 8;
        #pragma unroll
        for (int i = 0; i < 4; ++i)
            a[i] = *(const bf16x8*)(&As[(wm + i * 16 + lrow) * LDA + kof]);
        #pragma unroll
        for (int i = 0; i < 4; ++i)
            b[i] = *(const bf16x8*)(&Bs[(wn + i * 16 + lrow) * LDA + kof]);
        #pragma unroll
        for (int i = 0; i < 4; ++i)
            #pragma unroll
            for (int j = 0; j < 4; ++j)
                acc[i][j] = __builtin_amdgcn_mfma_f32_16x16x32_bf16(a[i], b[j], acc[i][j], 0, 0, 0);
    }

    // ---- epilogue: bias + pixel-shuffle scatter ----
    // C/D layout: col(n) = lane&15, row(m) = quad*4 + reg  [verified m89/m91]
    int sj = p & 15;
    #pragma unroll
    for (int j = 0; j < 4; ++j) {
        int o = n0 + wn + j * 16 + lrow;
        float bv = bias[(size_t)p * ODIM + o];
        int t = o >> 4, ui = (o >> 2) & 3, uj = o & 3;
        size_t base = ((size_t)t * 64 + si * 4 + ui) * 64 + sj * 4 + uj;
        #pragma unroll
        for (int i = 0; i < 4; ++i) {
            int brow = m0 + wm + i * 16 + quad * 4;
            #pragma unroll
            for (int r = 0; r < 4; ++r) {
                out[(size_t)(brow + r) * (64 * 64 * 64) + base] = acc[i][j][r] + bv;
            }
        }
    }
}

extern "C" void kernel_launch(void* const* d_in, const int* in_sizes, int n_in,
                              void* d_out, int out_size, void* d_ws, size_t ws_size,
                              hipStream_t stream) {
    const float* x    = (const float*)d_in[0];
    const float* W    = (const float*)d_in[1];
    const float* bias = (const float*)d_in[2];
    float* out = (float*)d_out;
    __hip_bfloat16* xp = (__hip_bfloat16*)d_ws;  // 256*256*64*2 = 8 MB

    transpose_convert<<<1024, 256, 0, stream>>>(x, xp);
    gemm_pixel<<<4096, 256, 0, stream>>>(xp, W, bias, out);
}